// Round 2
// baseline (665.398 us; speedup 1.0000x reference)
//
#include <hip/hip_runtime.h>

#define N_NODES 50000
#define N_EDGES 800000
#define DIM 128
#define NCLS 40

typedef __bf16 bf16x8_t __attribute__((ext_vector_type(8)));
typedef unsigned short us8_t __attribute__((ext_vector_type(8)));
typedef float f32x4_t __attribute__((ext_vector_type(4)));

static __device__ __forceinline__ float b2f(unsigned short h) {
    unsigned u = ((unsigned)h) << 16;
    return __builtin_bit_cast(float, u);
}
static __device__ __forceinline__ unsigned short f2b(float f) {
    unsigned u = __builtin_bit_cast(unsigned, f);
    u += 0x7FFFu + ((u >> 16) & 1u);   // RNE; values finite O(1)
    return (unsigned short)(u >> 16);
}

// ---------------- CSR build ----------------
__global__ __launch_bounds__(256) void count_deg(const int* __restrict__ dst,
                                                 int* __restrict__ deg) {
    int e = blockIdx.x * 256 + threadIdx.x;
    if (e < N_EDGES) atomicAdd(&deg[dst[e]], 1);
}

__global__ __launch_bounds__(1024) void scan_deg(const int* __restrict__ deg,
                                                 int* __restrict__ rs,
                                                 int* __restrict__ cursor,
                                                 float* __restrict__ dinv) {
    __shared__ int lds[1024];
    const int CH = (N_NODES + 1023) / 1024;   // 49
    int tid = threadIdx.x;
    int base = tid * CH;
    int s = 0;
    for (int i = 0; i < CH; ++i) {
        int idx = base + i;
        if (idx < N_NODES) s += deg[idx];
    }
    lds[tid] = s;
    __syncthreads();
    for (int off = 1; off < 1024; off <<= 1) {
        int v = lds[tid];
        int add = (tid >= off) ? lds[tid - off] : 0;
        __syncthreads();
        lds[tid] = v + add;
        __syncthreads();
    }
    int excl = (tid == 0) ? 0 : lds[tid - 1];
    for (int i = 0; i < CH; ++i) {
        int idx = base + i;
        if (idx < N_NODES) {
            int d = deg[idx];
            rs[idx] = excl;
            cursor[idx] = excl;
            dinv[idx] = (d > 0) ? (1.0f / (float)d) : 0.0f;
            excl += d;
        }
    }
}

__global__ __launch_bounds__(256) void fill_csr(const int* __restrict__ src,
                                                const int* __restrict__ dst,
                                                const float* __restrict__ mask,
                                                int* __restrict__ cursor,
                                                int* __restrict__ csr_src,
                                                float* __restrict__ csr_m) {
    int e = blockIdx.x * 256 + threadIdx.x;
    if (e < N_EDGES) {
        int d = dst[e];
        int pos = atomicAdd(&cursor[d], 1);
        csr_src[pos] = src[e];
        csr_m[pos] = mask[e];
    }
}

// ---------------- mean aggregation (gather) + residual add, f32 ----------------
// one wave per node; lane owns dims {2*lane, 2*lane+1}
__global__ __launch_bounds__(256) void agg_kernel(const float* __restrict__ x,
                                                  float* __restrict__ xin,
                                                  const int* __restrict__ rs,
                                                  const int* __restrict__ deg,
                                                  const float* __restrict__ dinv,
                                                  const int* __restrict__ csr_src,
                                                  const float* __restrict__ csr_m) {
    int lane = threadIdx.x & 63;
    int node = blockIdx.x * 4 + (threadIdx.x >> 6);
    if (node >= N_NODES) return;
    int cnt = deg[node];
    int start = rs[node];
    float acc0 = 0.f, acc1 = 0.f;
    for (int base = 0; base < cnt; base += 64) {
        int nb = cnt - base;
        if (nb > 64) nb = 64;
        int sidx = 0;
        int mbits = 0;
        if (lane < nb) {
            sidx = csr_src[start + base + lane];
            mbits = __builtin_bit_cast(int, csr_m[start + base + lane]);
        }
        #pragma unroll 4
        for (int j = 0; j < nb; ++j) {
            int ss = __builtin_amdgcn_readlane(sidx, j);
            float mm = __builtin_bit_cast(float, __builtin_amdgcn_readlane(mbits, j));
            float2 v = *(const float2*)(x + (size_t)ss * DIM + lane * 2);
            acc0 += mm * v.x;
            acc1 += mm * v.y;
        }
    }
    float di = dinv[node];
    float2 xp = *(const float2*)(x + (size_t)node * DIM + lane * 2);
    float2 o;
    o.x = xp.x + acc0 * di;
    o.y = xp.y + acc1 * di;
    *(float2*)(xin + (size_t)node * DIM + lane * 2) = o;
}

// ---------------- GEMM [N,128]x[128,128] + BN + ReLU, split-bf16 MFMA ----------------
__global__ __launch_bounds__(256) void gemm128_bn_relu(const float* __restrict__ xin,
                                                       const float* __restrict__ W,
                                                       const float* __restrict__ bias,
                                                       const float* __restrict__ gam,
                                                       const float* __restrict__ bet,
                                                       const float* __restrict__ rm,
                                                       const float* __restrict__ rv,
                                                       float* __restrict__ out) {
    __shared__ unsigned short WTh[128 * 136];   // hi(W^T), +8 pad (16B-aligned rows)
    __shared__ unsigned short WTl[128 * 136];   // lo(W^T)
    int tid = threadIdx.x;
    #pragma unroll
    for (int it = 0; it < 16; ++it) {
        int flat = (it * 256 + tid) * 4;       // element in row-major W [k][n]
        int k = flat >> 7;
        int n0 = flat & 127;                   // multiple of 4, no row crossing
        f32x4_t v = *(const f32x4_t*)(W + flat);
        #pragma unroll
        for (int j = 0; j < 4; ++j) {
            unsigned short hi = f2b(v[j]);
            float lo = v[j] - b2f(hi);
            WTh[(n0 + j) * 136 + k] = hi;
            WTl[(n0 + j) * 136 + k] = f2b(lo);
        }
    }
    __syncthreads();

    int wave = tid >> 6, lane = tid & 63;
    int m = lane & 15, quad = lane >> 4;
    int rbase = blockIdx.x * 64 + wave * 16;
    int arow = rbase + m;
    const float* ap = xin + (size_t)(arow < N_NODES ? arow : 0) * DIM;

    us8_t ah[4], al[4];
    #pragma unroll
    for (int kt = 0; kt < 4; ++kt) {
        f32x4_t p0 = *(const f32x4_t*)(ap + kt * 32 + quad * 8);
        f32x4_t p1 = *(const f32x4_t*)(ap + kt * 32 + quad * 8 + 4);
        #pragma unroll
        for (int j = 0; j < 4; ++j) {
            unsigned short h0 = f2b(p0[j]);
            unsigned short h1 = f2b(p1[j]);
            ah[kt][j] = h0;
            ah[kt][4 + j] = h1;
            al[kt][j] = f2b(p0[j] - b2f(h0));
            al[kt][4 + j] = f2b(p1[j] - b2f(h1));
        }
    }

    f32x4_t acc[8] = {};
    #pragma unroll
    for (int kt = 0; kt < 4; ++kt) {
        #pragma unroll
        for (int nt = 0; nt < 8; ++nt) {
            int boff = (nt * 16 + m) * 136 + kt * 32 + quad * 8;
            us8_t bh = *(const us8_t*)(&WTh[boff]);
            us8_t bl = *(const us8_t*)(&WTl[boff]);
            acc[nt] = __builtin_amdgcn_mfma_f32_16x16x32_bf16(
                __builtin_bit_cast(bf16x8_t, ah[kt]),
                __builtin_bit_cast(bf16x8_t, bh), acc[nt], 0, 0, 0);
            acc[nt] = __builtin_amdgcn_mfma_f32_16x16x32_bf16(
                __builtin_bit_cast(bf16x8_t, ah[kt]),
                __builtin_bit_cast(bf16x8_t, bl), acc[nt], 0, 0, 0);
            acc[nt] = __builtin_amdgcn_mfma_f32_16x16x32_bf16(
                __builtin_bit_cast(bf16x8_t, al[kt]),
                __builtin_bit_cast(bf16x8_t, bh), acc[nt], 0, 0, 0);
        }
    }

    #pragma unroll
    for (int nt = 0; nt < 8; ++nt) {
        int j = nt * 16 + m;   // output column for this lane
        float bj = bias[j];
        float sc = gam[j] * rsqrtf(rv[j] + 1e-5f);
        float sh = bet[j] - rm[j] * sc;
        #pragma unroll
        for (int i = 0; i < 4; ++i) {
            int r = rbase + quad * 4 + i;
            if (r < N_NODES) {
                float z = (acc[nt][i] + bj) * sc + sh;
                out[(size_t)r * DIM + j] = fmaxf(z, 0.f);
            }
        }
    }
}

// ---------------- fused final: h3 = relu(BN((h2+agg)@w2+b2)); out = (h2@wp+bp+h3)*0.5 ----------------
__global__ __launch_bounds__(256) void fused_final(const float* __restrict__ xin2,
                                                   const float* __restrict__ h2,
                                                   const float* __restrict__ w2,
                                                   const float* __restrict__ wp,
                                                   const float* __restrict__ b2,
                                                   const float* __restrict__ g2,
                                                   const float* __restrict__ be2,
                                                   const float* __restrict__ rm2,
                                                   const float* __restrict__ rv2,
                                                   const float* __restrict__ bp,
                                                   float* __restrict__ out) {
    __shared__ unsigned short W2Th[48 * 136];
    __shared__ unsigned short W2Tl[48 * 136];
    __shared__ unsigned short WPTh[48 * 136];
    __shared__ unsigned short WPTl[48 * 136];
    int tid = threadIdx.x;
    #pragma unroll
    for (int it = 0; it < 24; ++it) {
        int flat = it * 256 + tid;             // 48*128 = 6144
        int n = flat >> 7, k = flat & 127;
        float v2 = 0.f, vp = 0.f;
        if (n < NCLS) {
            v2 = w2[k * NCLS + n];
            vp = wp[k * NCLS + n];
        }
        unsigned short h2b = f2b(v2);
        unsigned short hpb = f2b(vp);
        W2Th[n * 136 + k] = h2b;
        W2Tl[n * 136 + k] = f2b(v2 - b2f(h2b));
        WPTh[n * 136 + k] = hpb;
        WPTl[n * 136 + k] = f2b(vp - b2f(hpb));
    }
    __syncthreads();

    int wave = tid >> 6, lane = tid & 63;
    int m = lane & 15, quad = lane >> 4;
    int rbase = blockIdx.x * 64 + wave * 16;
    int arow = rbase + m;
    size_t rowoff = (size_t)(arow < N_NODES ? arow : 0) * DIM;
    const float* ap2 = xin2 + rowoff;
    const float* aph = h2 + rowoff;

    us8_t a2h[4], a2l[4], ahh[4], ahl[4];
    #pragma unroll
    for (int kt = 0; kt < 4; ++kt) {
        f32x4_t p0 = *(const f32x4_t*)(ap2 + kt * 32 + quad * 8);
        f32x4_t p1 = *(const f32x4_t*)(ap2 + kt * 32 + quad * 8 + 4);
        f32x4_t q0 = *(const f32x4_t*)(aph + kt * 32 + quad * 8);
        f32x4_t q1 = *(const f32x4_t*)(aph + kt * 32 + quad * 8 + 4);
        #pragma unroll
        for (int j = 0; j < 4; ++j) {
            unsigned short h0 = f2b(p0[j]), h1 = f2b(p1[j]);
            a2h[kt][j] = h0; a2h[kt][4 + j] = h1;
            a2l[kt][j] = f2b(p0[j] - b2f(h0));
            a2l[kt][4 + j] = f2b(p1[j] - b2f(h1));
            unsigned short g0 = f2b(q0[j]), g1 = f2b(q1[j]);
            ahh[kt][j] = g0; ahh[kt][4 + j] = g1;
            ahl[kt][j] = f2b(q0[j] - b2f(g0));
            ahl[kt][4 + j] = f2b(q1[j] - b2f(g1));
        }
    }

    f32x4_t acc2[3] = {};
    f32x4_t accp[3] = {};
    #pragma unroll
    for (int kt = 0; kt < 4; ++kt) {
        #pragma unroll
        for (int nt = 0; nt < 3; ++nt) {
            int boff = (nt * 16 + m) * 136 + kt * 32 + quad * 8;
            us8_t b2hv = *(const us8_t*)(&W2Th[boff]);
            us8_t b2lv = *(const us8_t*)(&W2Tl[boff]);
            us8_t bphv = *(const us8_t*)(&WPTh[boff]);
            us8_t bplv = *(const us8_t*)(&WPTl[boff]);
            acc2[nt] = __builtin_amdgcn_mfma_f32_16x16x32_bf16(
                __builtin_bit_cast(bf16x8_t, a2h[kt]),
                __builtin_bit_cast(bf16x8_t, b2hv), acc2[nt], 0, 0, 0);
            acc2[nt] = __builtin_amdgcn_mfma_f32_16x16x32_bf16(
                __builtin_bit_cast(bf16x8_t, a2h[kt]),
                __builtin_bit_cast(bf16x8_t, b2lv), acc2[nt], 0, 0, 0);
            acc2[nt] = __builtin_amdgcn_mfma_f32_16x16x32_bf16(
                __builtin_bit_cast(bf16x8_t, a2l[kt]),
                __builtin_bit_cast(bf16x8_t, b2hv), acc2[nt], 0, 0, 0);
            accp[nt] = __builtin_amdgcn_mfma_f32_16x16x32_bf16(
                __builtin_bit_cast(bf16x8_t, ahh[kt]),
                __builtin_bit_cast(bf16x8_t, bphv), accp[nt], 0, 0, 0);
            accp[nt] = __builtin_amdgcn_mfma_f32_16x16x32_bf16(
                __builtin_bit_cast(bf16x8_t, ahh[kt]),
                __builtin_bit_cast(bf16x8_t, bplv), accp[nt], 0, 0, 0);
            accp[nt] = __builtin_amdgcn_mfma_f32_16x16x32_bf16(
                __builtin_bit_cast(bf16x8_t, ahl[kt]),
                __builtin_bit_cast(bf16x8_t, bphv), accp[nt], 0, 0, 0);
        }
    }

    #pragma unroll
    for (int nt = 0; nt < 3; ++nt) {
        int j = nt * 16 + m;
        int jc = (j < NCLS) ? j : (NCLS - 1);
        float b2j = b2[jc];
        float sc = g2[jc] * rsqrtf(rv2[jc] + 1e-5f);
        float sh = be2[jc] - rm2[jc] * sc;
        float bpj = bp[jc];
        #pragma unroll
        for (int i = 0; i < 4; ++i) {
            int r = rbase + quad * 4 + i;
            if (r < N_NODES && j < NCLS) {
                float z = (acc2[nt][i] + b2j) * sc + sh;
                z = fmaxf(z, 0.f);
                float p = accp[nt][i] + bpj;
                out[(size_t)r * NCLS + j] = (p + z) * 0.5f;
            }
        }
    }
}

extern "C" void kernel_launch(void* const* d_in, const int* in_sizes, int n_in,
                              void* d_out, int out_size, void* d_ws, size_t ws_size,
                              hipStream_t stream) {
    const float* h    = (const float*)d_in[0];
    const int* esrc   = (const int*)d_in[1];
    const int* edst   = (const int*)d_in[2];
    const float* mask = (const float*)d_in[3];
    const float* w0   = (const float*)d_in[4];
    const float* b0   = (const float*)d_in[5];
    const float* g0   = (const float*)d_in[6];
    const float* be0  = (const float*)d_in[7];
    const float* rm0  = (const float*)d_in[8];
    const float* rv0  = (const float*)d_in[9];
    const float* w1   = (const float*)d_in[10];
    const float* b1   = (const float*)d_in[11];
    const float* g1   = (const float*)d_in[12];
    const float* be1  = (const float*)d_in[13];
    const float* rm1  = (const float*)d_in[14];
    const float* rv1  = (const float*)d_in[15];
    const float* w2   = (const float*)d_in[16];
    const float* b2   = (const float*)d_in[17];
    const float* g2   = (const float*)d_in[18];
    const float* be2  = (const float*)d_in[19];
    const float* rm2  = (const float*)d_in[20];
    const float* rv2  = (const float*)d_in[21];
    const float* wp   = (const float*)d_in[22];
    const float* bp   = (const float*)d_in[23];

    char* ws = (char*)d_ws;
    size_t off = 0;
    auto alloc = [&](size_t bytes) {
        char* p = ws + off;
        off = (off + bytes + 255) & ~(size_t)255;
        return p;
    };
    int* deg      = (int*)alloc(N_NODES * 4);
    int* rs       = (int*)alloc(N_NODES * 4);
    int* cursor   = (int*)alloc(N_NODES * 4);
    float* dinv   = (float*)alloc(N_NODES * 4);
    int* csr_src  = (int*)alloc(N_EDGES * 4);
    float* csr_m  = (float*)alloc(N_EDGES * 4);
    float* xin    = (float*)alloc((size_t)N_NODES * DIM * 4);
    float* hb     = (float*)alloc((size_t)N_NODES * DIM * 4);

    hipMemsetAsync(deg, 0, N_NODES * 4, stream);

    const int EB = (N_EDGES + 255) / 256;
    const int AB = (N_NODES + 3) / 4;
    const int GB = (N_NODES + 63) / 64;

    count_deg<<<EB, 256, 0, stream>>>(edst, deg);
    scan_deg<<<1, 1024, 0, stream>>>(deg, rs, cursor, dinv);
    fill_csr<<<EB, 256, 0, stream>>>(esrc, edst, mask, cursor, csr_src, csr_m);

    // layer 0
    agg_kernel<<<AB, 256, 0, stream>>>(h, xin, rs, deg, dinv, csr_src, csr_m);
    gemm128_bn_relu<<<GB, 256, 0, stream>>>(xin, w0, b0, g0, be0, rm0, rv0, hb);
    // layer 1
    agg_kernel<<<AB, 256, 0, stream>>>(hb, xin, rs, deg, dinv, csr_src, csr_m);
    gemm128_bn_relu<<<GB, 256, 0, stream>>>(xin, w1, b1, g1, be1, rm1, rv1, hb);
    // layer 2 + predict, fused
    agg_kernel<<<AB, 256, 0, stream>>>(hb, xin, rs, deg, dinv, csr_src, csr_m);
    fused_final<<<GB, 256, 0, stream>>>(xin, hb, w2, wp, b2, g2, be2, rm2, rv2, bp,
                                        (float*)d_out);
}

// Round 3
// 523.470 us; speedup vs baseline: 1.2711x; 1.2711x over previous
//
#include <hip/hip_runtime.h>

#define N_NODES 50000
#define N_EDGES 800000
#define DIM 128
#define NCLS 40
#define SCAN_BLK 196   // ceil(50000/256)

typedef __bf16 bf16x8_t __attribute__((ext_vector_type(8)));
typedef unsigned short us8_t __attribute__((ext_vector_type(8)));
typedef float f32x4_t __attribute__((ext_vector_type(4)));

static __device__ __forceinline__ float b2f(unsigned short h) {
    unsigned u = ((unsigned)h) << 16;
    return __builtin_bit_cast(float, u);
}
static __device__ __forceinline__ unsigned short f2b(float f) {
    unsigned u = __builtin_bit_cast(unsigned, f);
    u += 0x7FFFu + ((u >> 16) & 1u);   // RNE; values finite O(1)
    return (unsigned short)(u >> 16);
}

// ---------------- CSR build ----------------
__global__ __launch_bounds__(256) void count_deg(const int* __restrict__ dst,
                                                 int* __restrict__ deg) {
    int e = blockIdx.x * 256 + threadIdx.x;
    if (e < N_EDGES) atomicAdd(&deg[dst[e]], 1);
}

// pass 1: per-block (256 nodes) partial sums of deg
__global__ __launch_bounds__(256) void scan_partial(const int* __restrict__ deg,
                                                    int* __restrict__ partial) {
    __shared__ int lds[256];
    int tid = threadIdx.x;
    int idx = blockIdx.x * 256 + tid;
    lds[tid] = (idx < N_NODES) ? deg[idx] : 0;
    __syncthreads();
    #pragma unroll
    for (int off = 128; off > 0; off >>= 1) {
        if (tid < off) lds[tid] += lds[tid + off];
        __syncthreads();
    }
    if (tid == 0) partial[blockIdx.x] = lds[0];
}

// pass 2: single small block scans the 196 partials -> exclusive block offsets
__global__ __launch_bounds__(256) void scan_blocks(const int* __restrict__ partial,
                                                   int* __restrict__ blk_off) {
    __shared__ int lds[256];
    int tid = threadIdx.x;
    lds[tid] = (tid < SCAN_BLK) ? partial[tid] : 0;
    __syncthreads();
    #pragma unroll
    for (int off = 1; off < 256; off <<= 1) {
        int v = lds[tid];
        int add = (tid >= off) ? lds[tid - off] : 0;
        __syncthreads();
        lds[tid] = v + add;
        __syncthreads();
    }
    if (tid < SCAN_BLK) blk_off[tid] = (tid == 0) ? 0 : lds[tid - 1];
}

// pass 3: per-block exclusive scan + block offset -> rs/cursor/dinv
__global__ __launch_bounds__(256) void scan_final(const int* __restrict__ deg,
                                                  const int* __restrict__ blk_off,
                                                  int* __restrict__ rs,
                                                  int* __restrict__ cursor,
                                                  float* __restrict__ dinv) {
    __shared__ int lds[256];
    int tid = threadIdx.x;
    int idx = blockIdx.x * 256 + tid;
    int d = (idx < N_NODES) ? deg[idx] : 0;
    lds[tid] = d;
    __syncthreads();
    #pragma unroll
    for (int off = 1; off < 256; off <<= 1) {
        int v = lds[tid];
        int add = (tid >= off) ? lds[tid - off] : 0;
        __syncthreads();
        lds[tid] = v + add;
        __syncthreads();
    }
    if (idx < N_NODES) {
        int excl = blk_off[blockIdx.x] + lds[tid] - d;
        rs[idx] = excl;
        cursor[idx] = excl;
        dinv[idx] = (d > 0) ? (1.0f / (float)d) : 0.0f;
    }
}

__global__ __launch_bounds__(256) void fill_csr(const int* __restrict__ src,
                                                const int* __restrict__ dst,
                                                const float* __restrict__ mask,
                                                int* __restrict__ cursor,
                                                int* __restrict__ csr_src,
                                                float* __restrict__ csr_m) {
    int e = blockIdx.x * 256 + threadIdx.x;
    if (e < N_EDGES) {
        int d = dst[e];
        int pos = atomicAdd(&cursor[d], 1);
        csr_src[pos] = src[e];
        csr_m[pos] = mask[e];
    }
}

// ---------------- mean aggregation (gather) + residual add, f32 ----------------
// one wave per node; lane owns dims {2*lane, 2*lane+1}
__global__ __launch_bounds__(256) void agg_kernel(const float* __restrict__ x,
                                                  float* __restrict__ xin,
                                                  const int* __restrict__ rs,
                                                  const int* __restrict__ deg,
                                                  const float* __restrict__ dinv,
                                                  const int* __restrict__ csr_src,
                                                  const float* __restrict__ csr_m) {
    int lane = threadIdx.x & 63;
    int node = blockIdx.x * 4 + (threadIdx.x >> 6);
    if (node >= N_NODES) return;
    int cnt = deg[node];
    int start = rs[node];
    float acc0 = 0.f, acc1 = 0.f;
    for (int base = 0; base < cnt; base += 64) {
        int nb = cnt - base;
        if (nb > 64) nb = 64;
        int sidx = 0;
        int mbits = 0;
        if (lane < nb) {
            sidx = csr_src[start + base + lane];
            mbits = __builtin_bit_cast(int, csr_m[start + base + lane]);
        }
        #pragma unroll 4
        for (int j = 0; j < nb; ++j) {
            int ss = __builtin_amdgcn_readlane(sidx, j);
            float mm = __builtin_bit_cast(float, __builtin_amdgcn_readlane(mbits, j));
            float2 v = *(const float2*)(x + (size_t)ss * DIM + lane * 2);
            acc0 += mm * v.x;
            acc1 += mm * v.y;
        }
    }
    float di = dinv[node];
    float2 xp = *(const float2*)(x + (size_t)node * DIM + lane * 2);
    float2 o;
    o.x = xp.x + acc0 * di;
    o.y = xp.y + acc1 * di;
    *(float2*)(xin + (size_t)node * DIM + lane * 2) = o;
}

// ---------------- GEMM [N,128]x[128,128] + BN + ReLU, split-bf16 MFMA ----------------
__global__ __launch_bounds__(256) void gemm128_bn_relu(const float* __restrict__ xin,
                                                       const float* __restrict__ W,
                                                       const float* __restrict__ bias,
                                                       const float* __restrict__ gam,
                                                       const float* __restrict__ bet,
                                                       const float* __restrict__ rm,
                                                       const float* __restrict__ rv,
                                                       float* __restrict__ out) {
    __shared__ unsigned short WTh[128 * 136];   // hi(W^T), +8 pad (16B-aligned rows)
    __shared__ unsigned short WTl[128 * 136];   // lo(W^T)
    int tid = threadIdx.x;
    #pragma unroll
    for (int it = 0; it < 16; ++it) {
        int flat = (it * 256 + tid) * 4;       // element in row-major W [k][n]
        int k = flat >> 7;
        int n0 = flat & 127;                   // multiple of 4, no row crossing
        f32x4_t v = *(const f32x4_t*)(W + flat);
        #pragma unroll
        for (int j = 0; j < 4; ++j) {
            unsigned short hi = f2b(v[j]);
            float lo = v[j] - b2f(hi);
            WTh[(n0 + j) * 136 + k] = hi;
            WTl[(n0 + j) * 136 + k] = f2b(lo);
        }
    }
    __syncthreads();

    int wave = tid >> 6, lane = tid & 63;
    int m = lane & 15, quad = lane >> 4;
    int rbase = blockIdx.x * 64 + wave * 16;
    int arow = rbase + m;
    const float* ap = xin + (size_t)(arow < N_NODES ? arow : 0) * DIM;

    us8_t ah[4], al[4];
    #pragma unroll
    for (int kt = 0; kt < 4; ++kt) {
        f32x4_t p0 = *(const f32x4_t*)(ap + kt * 32 + quad * 8);
        f32x4_t p1 = *(const f32x4_t*)(ap + kt * 32 + quad * 8 + 4);
        #pragma unroll
        for (int j = 0; j < 4; ++j) {
            unsigned short h0 = f2b(p0[j]);
            unsigned short h1 = f2b(p1[j]);
            ah[kt][j] = h0;
            ah[kt][4 + j] = h1;
            al[kt][j] = f2b(p0[j] - b2f(h0));
            al[kt][4 + j] = f2b(p1[j] - b2f(h1));
        }
    }

    f32x4_t acc[8] = {};
    #pragma unroll
    for (int kt = 0; kt < 4; ++kt) {
        #pragma unroll
        for (int nt = 0; nt < 8; ++nt) {
            int boff = (nt * 16 + m) * 136 + kt * 32 + quad * 8;
            us8_t bh = *(const us8_t*)(&WTh[boff]);
            us8_t bl = *(const us8_t*)(&WTl[boff]);
            acc[nt] = __builtin_amdgcn_mfma_f32_16x16x32_bf16(
                __builtin_bit_cast(bf16x8_t, ah[kt]),
                __builtin_bit_cast(bf16x8_t, bh), acc[nt], 0, 0, 0);
            acc[nt] = __builtin_amdgcn_mfma_f32_16x16x32_bf16(
                __builtin_bit_cast(bf16x8_t, ah[kt]),
                __builtin_bit_cast(bf16x8_t, bl), acc[nt], 0, 0, 0);
            acc[nt] = __builtin_amdgcn_mfma_f32_16x16x32_bf16(
                __builtin_bit_cast(bf16x8_t, al[kt]),
                __builtin_bit_cast(bf16x8_t, bh), acc[nt], 0, 0, 0);
        }
    }

    #pragma unroll
    for (int nt = 0; nt < 8; ++nt) {
        int j = nt * 16 + m;   // output column for this lane
        float bj = bias[j];
        float sc = gam[j] * rsqrtf(rv[j] + 1e-5f);
        float sh = bet[j] - rm[j] * sc;
        #pragma unroll
        for (int i = 0; i < 4; ++i) {
            int r = rbase + quad * 4 + i;
            if (r < N_NODES) {
                float z = (acc[nt][i] + bj) * sc + sh;
                out[(size_t)r * DIM + j] = fmaxf(z, 0.f);
            }
        }
    }
}

// ---------------- fused final: h3 = relu(BN((h2+agg)@w2+b2)); out = (h2@wp+bp+h3)*0.5 ----------------
__global__ __launch_bounds__(256) void fused_final(const float* __restrict__ xin2,
                                                   const float* __restrict__ h2,
                                                   const float* __restrict__ w2,
                                                   const float* __restrict__ wp,
                                                   const float* __restrict__ b2,
                                                   const float* __restrict__ g2,
                                                   const float* __restrict__ be2,
                                                   const float* __restrict__ rm2,
                                                   const float* __restrict__ rv2,
                                                   const float* __restrict__ bp,
                                                   float* __restrict__ out) {
    __shared__ unsigned short W2Th[48 * 136];
    __shared__ unsigned short W2Tl[48 * 136];
    __shared__ unsigned short WPTh[48 * 136];
    __shared__ unsigned short WPTl[48 * 136];
    int tid = threadIdx.x;
    #pragma unroll
    for (int it = 0; it < 24; ++it) {
        int flat = it * 256 + tid;             // 48*128 = 6144
        int n = flat >> 7, k = flat & 127;
        float v2 = 0.f, vp = 0.f;
        if (n < NCLS) {
            v2 = w2[k * NCLS + n];
            vp = wp[k * NCLS + n];
        }
        unsigned short h2b = f2b(v2);
        unsigned short hpb = f2b(vp);
        W2Th[n * 136 + k] = h2b;
        W2Tl[n * 136 + k] = f2b(v2 - b2f(h2b));
        WPTh[n * 136 + k] = hpb;
        WPTl[n * 136 + k] = f2b(vp - b2f(hpb));
    }
    __syncthreads();

    int wave = tid >> 6, lane = tid & 63;
    int m = lane & 15, quad = lane >> 4;
    int rbase = blockIdx.x * 64 + wave * 16;
    int arow = rbase + m;
    size_t rowoff = (size_t)(arow < N_NODES ? arow : 0) * DIM;
    const float* ap2 = xin2 + rowoff;
    const float* aph = h2 + rowoff;

    us8_t a2h[4], a2l[4], ahh[4], ahl[4];
    #pragma unroll
    for (int kt = 0; kt < 4; ++kt) {
        f32x4_t p0 = *(const f32x4_t*)(ap2 + kt * 32 + quad * 8);
        f32x4_t p1 = *(const f32x4_t*)(ap2 + kt * 32 + quad * 8 + 4);
        f32x4_t q0 = *(const f32x4_t*)(aph + kt * 32 + quad * 8);
        f32x4_t q1 = *(const f32x4_t*)(aph + kt * 32 + quad * 8 + 4);
        #pragma unroll
        for (int j = 0; j < 4; ++j) {
            unsigned short h0 = f2b(p0[j]), h1 = f2b(p1[j]);
            a2h[kt][j] = h0; a2h[kt][4 + j] = h1;
            a2l[kt][j] = f2b(p0[j] - b2f(h0));
            a2l[kt][4 + j] = f2b(p1[j] - b2f(h1));
            unsigned short g0 = f2b(q0[j]), g1 = f2b(q1[j]);
            ahh[kt][j] = g0; ahh[kt][4 + j] = g1;
            ahl[kt][j] = f2b(q0[j] - b2f(g0));
            ahl[kt][4 + j] = f2b(q1[j] - b2f(g1));
        }
    }

    f32x4_t acc2[3] = {};
    f32x4_t accp[3] = {};
    #pragma unroll
    for (int kt = 0; kt < 4; ++kt) {
        #pragma unroll
        for (int nt = 0; nt < 3; ++nt) {
            int boff = (nt * 16 + m) * 136 + kt * 32 + quad * 8;
            us8_t b2hv = *(const us8_t*)(&W2Th[boff]);
            us8_t b2lv = *(const us8_t*)(&W2Tl[boff]);
            us8_t bphv = *(const us8_t*)(&WPTh[boff]);
            us8_t bplv = *(const us8_t*)(&WPTl[boff]);
            acc2[nt] = __builtin_amdgcn_mfma_f32_16x16x32_bf16(
                __builtin_bit_cast(bf16x8_t, a2h[kt]),
                __builtin_bit_cast(bf16x8_t, b2hv), acc2[nt], 0, 0, 0);
            acc2[nt] = __builtin_amdgcn_mfma_f32_16x16x32_bf16(
                __builtin_bit_cast(bf16x8_t, a2h[kt]),
                __builtin_bit_cast(bf16x8_t, b2lv), acc2[nt], 0, 0, 0);
            acc2[nt] = __builtin_amdgcn_mfma_f32_16x16x32_bf16(
                __builtin_bit_cast(bf16x8_t, a2l[kt]),
                __builtin_bit_cast(bf16x8_t, b2hv), acc2[nt], 0, 0, 0);
            accp[nt] = __builtin_amdgcn_mfma_f32_16x16x32_bf16(
                __builtin_bit_cast(bf16x8_t, ahh[kt]),
                __builtin_bit_cast(bf16x8_t, bphv), accp[nt], 0, 0, 0);
            accp[nt] = __builtin_amdgcn_mfma_f32_16x16x32_bf16(
                __builtin_bit_cast(bf16x8_t, ahh[kt]),
                __builtin_bit_cast(bf16x8_t, bplv), accp[nt], 0, 0, 0);
            accp[nt] = __builtin_amdgcn_mfma_f32_16x16x32_bf16(
                __builtin_bit_cast(bf16x8_t, ahl[kt]),
                __builtin_bit_cast(bf16x8_t, bphv), accp[nt], 0, 0, 0);
        }
    }

    #pragma unroll
    for (int nt = 0; nt < 3; ++nt) {
        int j = nt * 16 + m;
        int jc = (j < NCLS) ? j : (NCLS - 1);
        float b2j = b2[jc];
        float sc = g2[jc] * rsqrtf(rv2[jc] + 1e-5f);
        float sh = be2[jc] - rm2[jc] * sc;
        float bpj = bp[jc];
        #pragma unroll
        for (int i = 0; i < 4; ++i) {
            int r = rbase + quad * 4 + i;
            if (r < N_NODES && j < NCLS) {
                float z = (acc2[nt][i] + b2j) * sc + sh;
                z = fmaxf(z, 0.f);
                float p = accp[nt][i] + bpj;
                out[(size_t)r * NCLS + j] = (p + z) * 0.5f;
            }
        }
    }
}

extern "C" void kernel_launch(void* const* d_in, const int* in_sizes, int n_in,
                              void* d_out, int out_size, void* d_ws, size_t ws_size,
                              hipStream_t stream) {
    const float* h    = (const float*)d_in[0];
    const int* esrc   = (const int*)d_in[1];
    const int* edst   = (const int*)d_in[2];
    const float* mask = (const float*)d_in[3];
    const float* w0   = (const float*)d_in[4];
    const float* b0   = (const float*)d_in[5];
    const float* g0   = (const float*)d_in[6];
    const float* be0  = (const float*)d_in[7];
    const float* rm0  = (const float*)d_in[8];
    const float* rv0  = (const float*)d_in[9];
    const float* w1   = (const float*)d_in[10];
    const float* b1   = (const float*)d_in[11];
    const float* g1   = (const float*)d_in[12];
    const float* be1  = (const float*)d_in[13];
    const float* rm1  = (const float*)d_in[14];
    const float* rv1  = (const float*)d_in[15];
    const float* w2   = (const float*)d_in[16];
    const float* b2   = (const float*)d_in[17];
    const float* g2   = (const float*)d_in[18];
    const float* be2  = (const float*)d_in[19];
    const float* rm2  = (const float*)d_in[20];
    const float* rv2  = (const float*)d_in[21];
    const float* wp   = (const float*)d_in[22];
    const float* bp   = (const float*)d_in[23];

    char* ws = (char*)d_ws;
    size_t off = 0;
    auto alloc = [&](size_t bytes) {
        char* p = ws + off;
        off = (off + bytes + 255) & ~(size_t)255;
        return p;
    };
    int* deg      = (int*)alloc(N_NODES * 4);
    int* rs       = (int*)alloc(N_NODES * 4);
    int* cursor   = (int*)alloc(N_NODES * 4);
    float* dinv   = (float*)alloc(N_NODES * 4);
    int* partial  = (int*)alloc(256 * 4);
    int* blk_off  = (int*)alloc(256 * 4);
    int* csr_src  = (int*)alloc(N_EDGES * 4);
    float* csr_m  = (float*)alloc(N_EDGES * 4);
    float* xin    = (float*)alloc((size_t)N_NODES * DIM * 4);
    float* hb     = (float*)alloc((size_t)N_NODES * DIM * 4);

    hipMemsetAsync(deg, 0, N_NODES * 4, stream);

    const int EB = (N_EDGES + 255) / 256;
    const int AB = (N_NODES + 3) / 4;
    const int GB = (N_NODES + 63) / 64;

    count_deg<<<EB, 256, 0, stream>>>(edst, deg);
    scan_partial<<<SCAN_BLK, 256, 0, stream>>>(deg, partial);
    scan_blocks<<<1, 256, 0, stream>>>(partial, blk_off);
    scan_final<<<SCAN_BLK, 256, 0, stream>>>(deg, blk_off, rs, cursor, dinv);
    fill_csr<<<EB, 256, 0, stream>>>(esrc, edst, mask, cursor, csr_src, csr_m);

    // layer 0
    agg_kernel<<<AB, 256, 0, stream>>>(h, xin, rs, deg, dinv, csr_src, csr_m);
    gemm128_bn_relu<<<GB, 256, 0, stream>>>(xin, w0, b0, g0, be0, rm0, rv0, hb);
    // layer 1
    agg_kernel<<<AB, 256, 0, stream>>>(hb, xin, rs, deg, dinv, csr_src, csr_m);
    gemm128_bn_relu<<<GB, 256, 0, stream>>>(xin, w1, b1, g1, be1, rm1, rv1, hb);
    // layer 2 + predict, fused
    agg_kernel<<<AB, 256, 0, stream>>>(hb, xin, rs, deg, dinv, csr_src, csr_m);
    fused_final<<<GB, 256, 0, stream>>>(xin, hb, w2, wp, b2, g2, be2, rm2, rv2, bp,
                                        (float*)d_out);
}

// Round 4
// 440.323 us; speedup vs baseline: 1.5112x; 1.1888x over previous
//
#include <hip/hip_runtime.h>

#define N_NODES 50000
#define N_EDGES 800000
#define DIM 128
#define NCLS 40
#define SCAN_BLK 196   // ceil(50000/256)

typedef __bf16 bf16x8_t __attribute__((ext_vector_type(8)));
typedef unsigned short us8_t __attribute__((ext_vector_type(8)));
typedef unsigned short us4_t __attribute__((ext_vector_type(4)));
typedef float f32x4_t __attribute__((ext_vector_type(4)));

static __device__ __forceinline__ float b2f(unsigned short h) {
    unsigned u = ((unsigned)h) << 16;
    return __builtin_bit_cast(float, u);
}
static __device__ __forceinline__ unsigned short f2b(float f) {
    unsigned u = __builtin_bit_cast(unsigned, f);
    u += 0x7FFFu + ((u >> 16) & 1u);   // RNE; values finite O(1)
    return (unsigned short)(u >> 16);
}

// ---------------- f32 -> bf16 shadow copy (for gather source) ----------------
__global__ __launch_bounds__(256) void to_bf16(const float* __restrict__ in,
                                               unsigned short* __restrict__ out) {
    int i = blockIdx.x * 256 + threadIdx.x;   // 4 elements per thread
    if (i * 4 < N_NODES * DIM) {
        f32x4_t v = *(const f32x4_t*)(in + (size_t)i * 4);
        us4_t o;
        #pragma unroll
        for (int j = 0; j < 4; ++j) o[j] = f2b(v[j]);
        *(us4_t*)(out + (size_t)i * 4) = o;
    }
}

// ---------------- CSR build ----------------
__global__ __launch_bounds__(256) void count_deg(const int* __restrict__ dst,
                                                 int* __restrict__ deg) {
    int e = blockIdx.x * 256 + threadIdx.x;
    if (e < N_EDGES) atomicAdd(&deg[dst[e]], 1);
}

__global__ __launch_bounds__(256) void scan_partial(const int* __restrict__ deg,
                                                    int* __restrict__ partial) {
    __shared__ int lds[256];
    int tid = threadIdx.x;
    int idx = blockIdx.x * 256 + tid;
    lds[tid] = (idx < N_NODES) ? deg[idx] : 0;
    __syncthreads();
    #pragma unroll
    for (int off = 128; off > 0; off >>= 1) {
        if (tid < off) lds[tid] += lds[tid + off];
        __syncthreads();
    }
    if (tid == 0) partial[blockIdx.x] = lds[0];
}

__global__ __launch_bounds__(256) void scan_blocks(const int* __restrict__ partial,
                                                   int* __restrict__ blk_off) {
    __shared__ int lds[256];
    int tid = threadIdx.x;
    lds[tid] = (tid < SCAN_BLK) ? partial[tid] : 0;
    __syncthreads();
    #pragma unroll
    for (int off = 1; off < 256; off <<= 1) {
        int v = lds[tid];
        int add = (tid >= off) ? lds[tid - off] : 0;
        __syncthreads();
        lds[tid] = v + add;
        __syncthreads();
    }
    if (tid < SCAN_BLK) blk_off[tid] = (tid == 0) ? 0 : lds[tid - 1];
}

__global__ __launch_bounds__(256) void scan_final(const int* __restrict__ deg,
                                                  const int* __restrict__ blk_off,
                                                  int* __restrict__ rs,
                                                  int* __restrict__ cursor,
                                                  float* __restrict__ dinv) {
    __shared__ int lds[256];
    int tid = threadIdx.x;
    int idx = blockIdx.x * 256 + tid;
    int d = (idx < N_NODES) ? deg[idx] : 0;
    lds[tid] = d;
    __syncthreads();
    #pragma unroll
    for (int off = 1; off < 256; off <<= 1) {
        int v = lds[tid];
        int add = (tid >= off) ? lds[tid - off] : 0;
        __syncthreads();
        lds[tid] = v + add;
        __syncthreads();
    }
    if (idx < N_NODES) {
        int excl = blk_off[blockIdx.x] + lds[tid] - d;
        rs[idx] = excl;
        cursor[idx] = excl;
        dinv[idx] = (d > 0) ? (1.0f / (float)d) : 0.0f;
    }
}

__global__ __launch_bounds__(256) void fill_csr(const int* __restrict__ src,
                                                const int* __restrict__ dst,
                                                const float* __restrict__ mask,
                                                int* __restrict__ cursor,
                                                int* __restrict__ csr_src,
                                                float* __restrict__ csr_m) {
    int e = blockIdx.x * 256 + threadIdx.x;
    if (e < N_EDGES) {
        int d = dst[e];
        int pos = atomicAdd(&cursor[d], 1);
        csr_src[pos] = src[e];
        csr_m[pos] = mask[e];
    }
}

// ---------------- mean aggregation: bf16 gather + f32 residual ----------------
// one wave per node; lane owns dims {2*lane, 2*lane+1}; 16 loads in flight
__global__ __launch_bounds__(256) void agg_kernel(const unsigned short* __restrict__ xb,
                                                  const float* __restrict__ x,
                                                  float* __restrict__ xin,
                                                  const int* __restrict__ rs,
                                                  const int* __restrict__ deg,
                                                  const float* __restrict__ dinv,
                                                  const int* __restrict__ csr_src,
                                                  const float* __restrict__ csr_m) {
    int lane = threadIdx.x & 63;
    int node = blockIdx.x * 4 + (threadIdx.x >> 6);
    if (node >= N_NODES) return;
    int cnt = deg[node];
    int start = rs[node];
    float acc0 = 0.f, acc1 = 0.f;
    for (int base = 0; base < cnt; base += 16) {
        int nb = cnt - base;
        if (nb > 16) nb = 16;
        int sidx = 0;
        int mbits = 0;
        if (lane < nb) {
            sidx = csr_src[start + base + lane];
            mbits = __builtin_bit_cast(int, csr_m[start + base + lane]);
        }
        unsigned vv[16];
        float mm[16];
        #pragma unroll
        for (int j = 0; j < 16; ++j) {
            int ss = __builtin_amdgcn_readlane(sidx, j);      // 0 for j>=nb
            mm[j] = __builtin_bit_cast(float, __builtin_amdgcn_readlane(mbits, j));
            vv[j] = *(const unsigned*)(xb + (size_t)ss * DIM + lane * 2);
        }
        #pragma unroll
        for (int j = 0; j < 16; ++j) {
            acc0 += mm[j] * b2f((unsigned short)(vv[j] & 0xFFFFu));
            acc1 += mm[j] * b2f((unsigned short)(vv[j] >> 16));
        }
    }
    float di = dinv[node];
    float2 xp = *(const float2*)(x + (size_t)node * DIM + lane * 2);
    float2 o;
    o.x = xp.x + acc0 * di;
    o.y = xp.y + acc1 * di;
    *(float2*)(xin + (size_t)node * DIM + lane * 2) = o;
}

// ---------------- GEMM [N,128]x[128,128] + BN + ReLU, split-bf16 MFMA ----------------
// writes f32 out + bf16 shadow outb (gather source for next layer)
__global__ __launch_bounds__(256) void gemm128_bn_relu(const float* __restrict__ xin,
                                                       const float* __restrict__ W,
                                                       const float* __restrict__ bias,
                                                       const float* __restrict__ gam,
                                                       const float* __restrict__ bet,
                                                       const float* __restrict__ rm,
                                                       const float* __restrict__ rv,
                                                       float* __restrict__ out,
                                                       unsigned short* __restrict__ outb) {
    __shared__ unsigned short WTh[128 * 136];   // hi(W^T), +8 pad
    __shared__ unsigned short WTl[128 * 136];   // lo(W^T)
    int tid = threadIdx.x;
    #pragma unroll
    for (int it = 0; it < 16; ++it) {
        int flat = (it * 256 + tid) * 4;       // element in row-major W [k][n]
        int k = flat >> 7;
        int n0 = flat & 127;
        f32x4_t v = *(const f32x4_t*)(W + flat);
        #pragma unroll
        for (int j = 0; j < 4; ++j) {
            unsigned short hi = f2b(v[j]);
            float lo = v[j] - b2f(hi);
            WTh[(n0 + j) * 136 + k] = hi;
            WTl[(n0 + j) * 136 + k] = f2b(lo);
        }
    }
    __syncthreads();

    int wave = tid >> 6, lane = tid & 63;
    int m = lane & 15, quad = lane >> 4;
    int rbase = blockIdx.x * 64 + wave * 16;
    int arow = rbase + m;
    const float* ap = xin + (size_t)(arow < N_NODES ? arow : 0) * DIM;

    us8_t ah[4], al[4];
    #pragma unroll
    for (int kt = 0; kt < 4; ++kt) {
        f32x4_t p0 = *(const f32x4_t*)(ap + kt * 32 + quad * 8);
        f32x4_t p1 = *(const f32x4_t*)(ap + kt * 32 + quad * 8 + 4);
        #pragma unroll
        for (int j = 0; j < 4; ++j) {
            unsigned short h0 = f2b(p0[j]);
            unsigned short h1 = f2b(p1[j]);
            ah[kt][j] = h0;
            ah[kt][4 + j] = h1;
            al[kt][j] = f2b(p0[j] - b2f(h0));
            al[kt][4 + j] = f2b(p1[j] - b2f(h1));
        }
    }

    f32x4_t acc[8] = {};
    #pragma unroll
    for (int kt = 0; kt < 4; ++kt) {
        #pragma unroll
        for (int nt = 0; nt < 8; ++nt) {
            int boff = (nt * 16 + m) * 136 + kt * 32 + quad * 8;
            us8_t bh = *(const us8_t*)(&WTh[boff]);
            us8_t bl = *(const us8_t*)(&WTl[boff]);
            acc[nt] = __builtin_amdgcn_mfma_f32_16x16x32_bf16(
                __builtin_bit_cast(bf16x8_t, ah[kt]),
                __builtin_bit_cast(bf16x8_t, bh), acc[nt], 0, 0, 0);
            acc[nt] = __builtin_amdgcn_mfma_f32_16x16x32_bf16(
                __builtin_bit_cast(bf16x8_t, ah[kt]),
                __builtin_bit_cast(bf16x8_t, bl), acc[nt], 0, 0, 0);
            acc[nt] = __builtin_amdgcn_mfma_f32_16x16x32_bf16(
                __builtin_bit_cast(bf16x8_t, al[kt]),
                __builtin_bit_cast(bf16x8_t, bh), acc[nt], 0, 0, 0);
        }
    }

    #pragma unroll
    for (int nt = 0; nt < 8; ++nt) {
        int j = nt * 16 + m;
        float bj = bias[j];
        float sc = gam[j] * rsqrtf(rv[j] + 1e-5f);
        float sh = bet[j] - rm[j] * sc;
        #pragma unroll
        for (int i = 0; i < 4; ++i) {
            int r = rbase + quad * 4 + i;
            if (r < N_NODES) {
                float z = fmaxf((acc[nt][i] + bj) * sc + sh, 0.f);
                out[(size_t)r * DIM + j] = z;
                outb[(size_t)r * DIM + j] = f2b(z);
            }
        }
    }
}

// ---------------- fused final: h3 = relu(BN((h2+agg)@w2+b2)); out = (h2@wp+bp+h3)*0.5 ----------------
__global__ __launch_bounds__(256) void fused_final(const float* __restrict__ xin2,
                                                   const float* __restrict__ h2,
                                                   const float* __restrict__ w2,
                                                   const float* __restrict__ wp,
                                                   const float* __restrict__ b2,
                                                   const float* __restrict__ g2,
                                                   const float* __restrict__ be2,
                                                   const float* __restrict__ rm2,
                                                   const float* __restrict__ rv2,
                                                   const float* __restrict__ bp,
                                                   float* __restrict__ out) {
    __shared__ unsigned short W2Th[48 * 136];
    __shared__ unsigned short W2Tl[48 * 136];
    __shared__ unsigned short WPTh[48 * 136];
    __shared__ unsigned short WPTl[48 * 136];
    int tid = threadIdx.x;
    #pragma unroll
    for (int it = 0; it < 24; ++it) {
        int flat = it * 256 + tid;             // 48*128 = 6144
        int n = flat >> 7, k = flat & 127;
        float v2 = 0.f, vp = 0.f;
        if (n < NCLS) {
            v2 = w2[k * NCLS + n];
            vp = wp[k * NCLS + n];
        }
        unsigned short h2b = f2b(v2);
        unsigned short hpb = f2b(vp);
        W2Th[n * 136 + k] = h2b;
        W2Tl[n * 136 + k] = f2b(v2 - b2f(h2b));
        WPTh[n * 136 + k] = hpb;
        WPTl[n * 136 + k] = f2b(vp - b2f(hpb));
    }
    __syncthreads();

    int wave = tid >> 6, lane = tid & 63;
    int m = lane & 15, quad = lane >> 4;
    int rbase = blockIdx.x * 64 + wave * 16;
    int arow = rbase + m;
    size_t rowoff = (size_t)(arow < N_NODES ? arow : 0) * DIM;
    const float* ap2 = xin2 + rowoff;
    const float* aph = h2 + rowoff;

    us8_t a2h[4], a2l[4], ahh[4], ahl[4];
    #pragma unroll
    for (int kt = 0; kt < 4; ++kt) {
        f32x4_t p0 = *(const f32x4_t*)(ap2 + kt * 32 + quad * 8);
        f32x4_t p1 = *(const f32x4_t*)(ap2 + kt * 32 + quad * 8 + 4);
        f32x4_t q0 = *(const f32x4_t*)(aph + kt * 32 + quad * 8);
        f32x4_t q1 = *(const f32x4_t*)(aph + kt * 32 + quad * 8 + 4);
        #pragma unroll
        for (int j = 0; j < 4; ++j) {
            unsigned short h0 = f2b(p0[j]), h1 = f2b(p1[j]);
            a2h[kt][j] = h0; a2h[kt][4 + j] = h1;
            a2l[kt][j] = f2b(p0[j] - b2f(h0));
            a2l[kt][4 + j] = f2b(p1[j] - b2f(h1));
            unsigned short g0 = f2b(q0[j]), g1 = f2b(q1[j]);
            ahh[kt][j] = g0; ahh[kt][4 + j] = g1;
            ahl[kt][j] = f2b(q0[j] - b2f(g0));
            ahl[kt][4 + j] = f2b(q1[j] - b2f(g1));
        }
    }

    f32x4_t acc2[3] = {};
    f32x4_t accp[3] = {};
    #pragma unroll
    for (int kt = 0; kt < 4; ++kt) {
        #pragma unroll
        for (int nt = 0; nt < 3; ++nt) {
            int boff = (nt * 16 + m) * 136 + kt * 32 + quad * 8;
            us8_t b2hv = *(const us8_t*)(&W2Th[boff]);
            us8_t b2lv = *(const us8_t*)(&W2Tl[boff]);
            us8_t bphv = *(const us8_t*)(&WPTh[boff]);
            us8_t bplv = *(const us8_t*)(&WPTl[boff]);
            acc2[nt] = __builtin_amdgcn_mfma_f32_16x16x32_bf16(
                __builtin_bit_cast(bf16x8_t, a2h[kt]),
                __builtin_bit_cast(bf16x8_t, b2hv), acc2[nt], 0, 0, 0);
            acc2[nt] = __builtin_amdgcn_mfma_f32_16x16x32_bf16(
                __builtin_bit_cast(bf16x8_t, a2h[kt]),
                __builtin_bit_cast(bf16x8_t, b2lv), acc2[nt], 0, 0, 0);
            acc2[nt] = __builtin_amdgcn_mfma_f32_16x16x32_bf16(
                __builtin_bit_cast(bf16x8_t, a2l[kt]),
                __builtin_bit_cast(bf16x8_t, b2hv), acc2[nt], 0, 0, 0);
            accp[nt] = __builtin_amdgcn_mfma_f32_16x16x32_bf16(
                __builtin_bit_cast(bf16x8_t, ahh[kt]),
                __builtin_bit_cast(bf16x8_t, bphv), accp[nt], 0, 0, 0);
            accp[nt] = __builtin_amdgcn_mfma_f32_16x16x32_bf16(
                __builtin_bit_cast(bf16x8_t, ahh[kt]),
                __builtin_bit_cast(bf16x8_t, bplv), accp[nt], 0, 0, 0);
            accp[nt] = __builtin_amdgcn_mfma_f32_16x16x32_bf16(
                __builtin_bit_cast(bf16x8_t, ahl[kt]),
                __builtin_bit_cast(bf16x8_t, bphv), accp[nt], 0, 0, 0);
        }
    }

    #pragma unroll
    for (int nt = 0; nt < 3; ++nt) {
        int j = nt * 16 + m;
        int jc = (j < NCLS) ? j : (NCLS - 1);
        float b2j = b2[jc];
        float sc = g2[jc] * rsqrtf(rv2[jc] + 1e-5f);
        float sh = be2[jc] - rm2[jc] * sc;
        float bpj = bp[jc];
        #pragma unroll
        for (int i = 0; i < 4; ++i) {
            int r = rbase + quad * 4 + i;
            if (r < N_NODES && j < NCLS) {
                float z = fmaxf((acc2[nt][i] + b2j) * sc + sh, 0.f);
                float p = accp[nt][i] + bpj;
                out[(size_t)r * NCLS + j] = (p + z) * 0.5f;
            }
        }
    }
}

extern "C" void kernel_launch(void* const* d_in, const int* in_sizes, int n_in,
                              void* d_out, int out_size, void* d_ws, size_t ws_size,
                              hipStream_t stream) {
    const float* h    = (const float*)d_in[0];
    const int* esrc   = (const int*)d_in[1];
    const int* edst   = (const int*)d_in[2];
    const float* mask = (const float*)d_in[3];
    const float* w0   = (const float*)d_in[4];
    const float* b0   = (const float*)d_in[5];
    const float* g0   = (const float*)d_in[6];
    const float* be0  = (const float*)d_in[7];
    const float* rm0  = (const float*)d_in[8];
    const float* rv0  = (const float*)d_in[9];
    const float* w1   = (const float*)d_in[10];
    const float* b1   = (const float*)d_in[11];
    const float* g1   = (const float*)d_in[12];
    const float* be1  = (const float*)d_in[13];
    const float* rm1  = (const float*)d_in[14];
    const float* rv1  = (const float*)d_in[15];
    const float* w2   = (const float*)d_in[16];
    const float* b2   = (const float*)d_in[17];
    const float* g2   = (const float*)d_in[18];
    const float* be2  = (const float*)d_in[19];
    const float* rm2  = (const float*)d_in[20];
    const float* rv2  = (const float*)d_in[21];
    const float* wp   = (const float*)d_in[22];
    const float* bp   = (const float*)d_in[23];

    char* ws = (char*)d_ws;
    size_t off = 0;
    auto alloc = [&](size_t bytes) {
        char* p = ws + off;
        off = (off + bytes + 255) & ~(size_t)255;
        return p;
    };
    int* deg      = (int*)alloc(N_NODES * 4);
    int* rs       = (int*)alloc(N_NODES * 4);
    int* cursor   = (int*)alloc(N_NODES * 4);
    float* dinv   = (float*)alloc(N_NODES * 4);
    int* partial  = (int*)alloc(256 * 4);
    int* blk_off  = (int*)alloc(256 * 4);
    int* csr_src  = (int*)alloc(N_EDGES * 4);
    float* csr_m  = (float*)alloc(N_EDGES * 4);
    float* xin    = (float*)alloc((size_t)N_NODES * DIM * 4);
    float* hb     = (float*)alloc((size_t)N_NODES * DIM * 4);
    unsigned short* xb16 = (unsigned short*)alloc((size_t)N_NODES * DIM * 2);
    unsigned short* hb16 = (unsigned short*)alloc((size_t)N_NODES * DIM * 2);

    hipMemsetAsync(deg, 0, N_NODES * 4, stream);

    const int EB = (N_EDGES + 255) / 256;
    const int AB = (N_NODES + 3) / 4;
    const int GB = (N_NODES + 63) / 64;
    const int CB = (N_NODES * DIM / 4 + 255) / 256;

    count_deg<<<EB, 256, 0, stream>>>(edst, deg);
    scan_partial<<<SCAN_BLK, 256, 0, stream>>>(deg, partial);
    scan_blocks<<<1, 256, 0, stream>>>(partial, blk_off);
    scan_final<<<SCAN_BLK, 256, 0, stream>>>(deg, blk_off, rs, cursor, dinv);
    fill_csr<<<EB, 256, 0, stream>>>(esrc, edst, mask, cursor, csr_src, csr_m);
    to_bf16<<<CB, 256, 0, stream>>>(h, xb16);

    // layer 0
    agg_kernel<<<AB, 256, 0, stream>>>(xb16, h, xin, rs, deg, dinv, csr_src, csr_m);
    gemm128_bn_relu<<<GB, 256, 0, stream>>>(xin, w0, b0, g0, be0, rm0, rv0, hb, hb16);
    // layer 1
    agg_kernel<<<AB, 256, 0, stream>>>(hb16, hb, xin, rs, deg, dinv, csr_src, csr_m);
    gemm128_bn_relu<<<GB, 256, 0, stream>>>(xin, w1, b1, g1, be1, rm1, rv1, hb, hb16);
    // layer 2 + predict, fused
    agg_kernel<<<AB, 256, 0, stream>>>(hb16, hb, xin, rs, deg, dinv, csr_src, csr_m);
    fused_final<<<GB, 256, 0, stream>>>(xin, hb, w2, wp, b2, g2, be2, rm2, rv2, bp,
                                        (float*)d_out);
}

// Round 5
// 423.024 us; speedup vs baseline: 1.5730x; 1.0409x over previous
//
#include <hip/hip_runtime.h>

#define N_NODES 50000
#define N_EDGES 800000
#define DIM 128
#define NCLS 40
#define SCAN_BLK 196   // ceil(50000/256)

typedef __bf16 bf16x8_t __attribute__((ext_vector_type(8)));
typedef unsigned short us8_t __attribute__((ext_vector_type(8)));
typedef unsigned short us4_t __attribute__((ext_vector_type(4)));
typedef float f32x4_t __attribute__((ext_vector_type(4)));

static __device__ __forceinline__ float b2f(unsigned short h) {
    unsigned u = ((unsigned)h) << 16;
    return __builtin_bit_cast(float, u);
}
static __device__ __forceinline__ unsigned short f2b(float f) {
    unsigned u = __builtin_bit_cast(unsigned, f);
    u += 0x7FFFu + ((u >> 16) & 1u);   // RNE; values finite O(1)
    return (unsigned short)(u >> 16);
}

// ---------------- fused: degree count + f32->bf16 shadow of h ----------------
// grid = 3125 blocks x 256: one edge per thread; 8 h-elements per thread
__global__ __launch_bounds__(256) void prep_kernel(const int* __restrict__ dst,
                                                   int* __restrict__ deg,
                                                   const float* __restrict__ hin,
                                                   unsigned short* __restrict__ hb16) {
    int t = blockIdx.x * 256 + threadIdx.x;
    if (t < N_EDGES) atomicAdd(&deg[dst[t]], 1);
    // bf16 conversion: 800000 threads x 8 = 6.4M elements
    size_t e0 = (size_t)t * 8;
    f32x4_t v0 = *(const f32x4_t*)(hin + e0);
    f32x4_t v1 = *(const f32x4_t*)(hin + e0 + 4);
    us8_t o;
    #pragma unroll
    for (int j = 0; j < 4; ++j) { o[j] = f2b(v0[j]); o[4 + j] = f2b(v1[j]); }
    *(us8_t*)(hb16 + e0) = o;
}

// ---------------- hierarchical exclusive scan of deg ----------------
__global__ __launch_bounds__(256) void scan_partial(const int* __restrict__ deg,
                                                    int* __restrict__ partial) {
    __shared__ int lds[256];
    int tid = threadIdx.x;
    int idx = blockIdx.x * 256 + tid;
    lds[tid] = (idx < N_NODES) ? deg[idx] : 0;
    __syncthreads();
    #pragma unroll
    for (int off = 128; off > 0; off >>= 1) {
        if (tid < off) lds[tid] += lds[tid + off];
        __syncthreads();
    }
    if (tid == 0) partial[blockIdx.x] = lds[0];
}

__global__ __launch_bounds__(256) void scan_blocks(const int* __restrict__ partial,
                                                   int* __restrict__ blk_off) {
    __shared__ int lds[256];
    int tid = threadIdx.x;
    lds[tid] = (tid < SCAN_BLK) ? partial[tid] : 0;
    __syncthreads();
    #pragma unroll
    for (int off = 1; off < 256; off <<= 1) {
        int v = lds[tid];
        int add = (tid >= off) ? lds[tid - off] : 0;
        __syncthreads();
        lds[tid] = v + add;
        __syncthreads();
    }
    if (tid < SCAN_BLK) blk_off[tid] = (tid == 0) ? 0 : lds[tid - 1];
}

__global__ __launch_bounds__(256) void scan_final(const int* __restrict__ deg,
                                                  const int* __restrict__ blk_off,
                                                  int* __restrict__ rs,
                                                  int* __restrict__ cursor,
                                                  float* __restrict__ dinv) {
    __shared__ int lds[256];
    int tid = threadIdx.x;
    int idx = blockIdx.x * 256 + tid;
    int d = (idx < N_NODES) ? deg[idx] : 0;
    lds[tid] = d;
    __syncthreads();
    #pragma unroll
    for (int off = 1; off < 256; off <<= 1) {
        int v = lds[tid];
        int add = (tid >= off) ? lds[tid - off] : 0;
        __syncthreads();
        lds[tid] = v + add;
        __syncthreads();
    }
    if (idx < N_NODES) {
        int excl = blk_off[blockIdx.x] + lds[tid] - d;
        rs[idx] = excl;
        cursor[idx] = excl;
        dinv[idx] = (d > 0) ? (1.0f / (float)d) : 0.0f;
    }
}

// ---------------- CSR fill: ONE packed 4B store per edge ----------------
// entry = src (16b, N<65536) | bf16(mask) << 16
__global__ __launch_bounds__(256) void fill_csr(const int* __restrict__ src,
                                                const int* __restrict__ dst,
                                                const float* __restrict__ mask,
                                                int* __restrict__ cursor,
                                                unsigned* __restrict__ csr) {
    int e = blockIdx.x * 256 + threadIdx.x;
    if (e < N_EDGES) {
        int d = dst[e];
        int pos = atomicAdd(&cursor[d], 1);
        csr[pos] = (unsigned)src[e] | ((unsigned)f2b(mask[e]) << 16);
    }
}

// ---------------- mean aggregation: bf16 gather + f32 residual ----------------
// one wave per node; lane owns dims {2*lane, 2*lane+1}; 16 loads in flight
__global__ __launch_bounds__(256) void agg_kernel(const unsigned short* __restrict__ xb,
                                                  const float* __restrict__ x,
                                                  float* __restrict__ xin,
                                                  const int* __restrict__ rs,
                                                  const int* __restrict__ deg,
                                                  const float* __restrict__ dinv,
                                                  const unsigned* __restrict__ csr) {
    int lane = threadIdx.x & 63;
    int node = blockIdx.x * 4 + (threadIdx.x >> 6);
    if (node >= N_NODES) return;
    int cnt = deg[node];
    int start = rs[node];
    float acc0 = 0.f, acc1 = 0.f;
    for (int base = 0; base < cnt; base += 16) {
        int nb = cnt - base;
        if (nb > 16) nb = 16;
        unsigned pk = 0;
        if (lane < nb) pk = csr[start + base + lane];
        unsigned vv[16];
        float mm[16];
        #pragma unroll
        for (int j = 0; j < 16; ++j) {
            unsigned p = (unsigned)__builtin_amdgcn_readlane((int)pk, j);  // 0 for j>=nb
            mm[j] = b2f((unsigned short)(p >> 16));
            vv[j] = *(const unsigned*)(xb + (size_t)(p & 0xFFFFu) * DIM + lane * 2);
        }
        #pragma unroll
        for (int j = 0; j < 16; ++j) {
            acc0 += mm[j] * b2f((unsigned short)(vv[j] & 0xFFFFu));
            acc1 += mm[j] * b2f((unsigned short)(vv[j] >> 16));
        }
    }
    float di = dinv[node];
    float2 xp = *(const float2*)(x + (size_t)node * DIM + lane * 2);
    float2 o;
    o.x = xp.x + acc0 * di;
    o.y = xp.y + acc1 * di;
    *(float2*)(xin + (size_t)node * DIM + lane * 2) = o;
}

// ---------------- GEMM [N,128]x[128,128] + BN + ReLU, split-bf16 MFMA ----------------
// writes f32 out + bf16 shadow outb (gather source for next layer)
__global__ __launch_bounds__(256) void gemm128_bn_relu(const float* __restrict__ xin,
                                                       const float* __restrict__ W,
                                                       const float* __restrict__ bias,
                                                       const float* __restrict__ gam,
                                                       const float* __restrict__ bet,
                                                       const float* __restrict__ rm,
                                                       const float* __restrict__ rv,
                                                       float* __restrict__ out,
                                                       unsigned short* __restrict__ outb) {
    __shared__ unsigned short WTh[128 * 136];   // hi(W^T), +8 pad
    __shared__ unsigned short WTl[128 * 136];   // lo(W^T)
    int tid = threadIdx.x;
    #pragma unroll
    for (int it = 0; it < 16; ++it) {
        int flat = (it * 256 + tid) * 4;       // element in row-major W [k][n]
        int k = flat >> 7;
        int n0 = flat & 127;
        f32x4_t v = *(const f32x4_t*)(W + flat);
        #pragma unroll
        for (int j = 0; j < 4; ++j) {
            unsigned short hi = f2b(v[j]);
            float lo = v[j] - b2f(hi);
            WTh[(n0 + j) * 136 + k] = hi;
            WTl[(n0 + j) * 136 + k] = f2b(lo);
        }
    }
    __syncthreads();

    int wave = tid >> 6, lane = tid & 63;
    int m = lane & 15, quad = lane >> 4;
    int rbase = blockIdx.x * 64 + wave * 16;
    int arow = rbase + m;
    const float* ap = xin + (size_t)(arow < N_NODES ? arow : 0) * DIM;

    us8_t ah[4], al[4];
    #pragma unroll
    for (int kt = 0; kt < 4; ++kt) {
        f32x4_t p0 = *(const f32x4_t*)(ap + kt * 32 + quad * 8);
        f32x4_t p1 = *(const f32x4_t*)(ap + kt * 32 + quad * 8 + 4);
        #pragma unroll
        for (int j = 0; j < 4; ++j) {
            unsigned short h0 = f2b(p0[j]);
            unsigned short h1 = f2b(p1[j]);
            ah[kt][j] = h0;
            ah[kt][4 + j] = h1;
            al[kt][j] = f2b(p0[j] - b2f(h0));
            al[kt][4 + j] = f2b(p1[j] - b2f(h1));
        }
    }

    f32x4_t acc[8] = {};
    #pragma unroll
    for (int kt = 0; kt < 4; ++kt) {
        #pragma unroll
        for (int nt = 0; nt < 8; ++nt) {
            int boff = (nt * 16 + m) * 136 + kt * 32 + quad * 8;
            us8_t bh = *(const us8_t*)(&WTh[boff]);
            us8_t bl = *(const us8_t*)(&WTl[boff]);
            acc[nt] = __builtin_amdgcn_mfma_f32_16x16x32_bf16(
                __builtin_bit_cast(bf16x8_t, ah[kt]),
                __builtin_bit_cast(bf16x8_t, bh), acc[nt], 0, 0, 0);
            acc[nt] = __builtin_amdgcn_mfma_f32_16x16x32_bf16(
                __builtin_bit_cast(bf16x8_t, ah[kt]),
                __builtin_bit_cast(bf16x8_t, bl), acc[nt], 0, 0, 0);
            acc[nt] = __builtin_amdgcn_mfma_f32_16x16x32_bf16(
                __builtin_bit_cast(bf16x8_t, al[kt]),
                __builtin_bit_cast(bf16x8_t, bh), acc[nt], 0, 0, 0);
        }
    }

    #pragma unroll
    for (int nt = 0; nt < 8; ++nt) {
        int j = nt * 16 + m;
        float bj = bias[j];
        float sc = gam[j] * rsqrtf(rv[j] + 1e-5f);
        float sh = bet[j] - rm[j] * sc;
        #pragma unroll
        for (int i = 0; i < 4; ++i) {
            int r = rbase + quad * 4 + i;
            if (r < N_NODES) {
                float z = fmaxf((acc[nt][i] + bj) * sc + sh, 0.f);
                out[(size_t)r * DIM + j] = z;
                outb[(size_t)r * DIM + j] = f2b(z);
            }
        }
    }
}

// ---------------- fused final: h3 = relu(BN((h2+agg)@w2+b2)); out = (h2@wp+bp+h3)*0.5 ----------------
__global__ __launch_bounds__(256) void fused_final(const float* __restrict__ xin2,
                                                   const float* __restrict__ h2,
                                                   const float* __restrict__ w2,
                                                   const float* __restrict__ wp,
                                                   const float* __restrict__ b2,
                                                   const float* __restrict__ g2,
                                                   const float* __restrict__ be2,
                                                   const float* __restrict__ rm2,
                                                   const float* __restrict__ rv2,
                                                   const float* __restrict__ bp,
                                                   float* __restrict__ out) {
    __shared__ unsigned short W2Th[48 * 136];
    __shared__ unsigned short W2Tl[48 * 136];
    __shared__ unsigned short WPTh[48 * 136];
    __shared__ unsigned short WPTl[48 * 136];
    int tid = threadIdx.x;
    #pragma unroll
    for (int it = 0; it < 24; ++it) {
        int flat = it * 256 + tid;             // 48*128 = 6144
        int n = flat >> 7, k = flat & 127;
        float v2 = 0.f, vp = 0.f;
        if (n < NCLS) {
            v2 = w2[k * NCLS + n];
            vp = wp[k * NCLS + n];
        }
        unsigned short h2b = f2b(v2);
        unsigned short hpb = f2b(vp);
        W2Th[n * 136 + k] = h2b;
        W2Tl[n * 136 + k] = f2b(v2 - b2f(h2b));
        WPTh[n * 136 + k] = hpb;
        WPTl[n * 136 + k] = f2b(vp - b2f(hpb));
    }
    __syncthreads();

    int wave = tid >> 6, lane = tid & 63;
    int m = lane & 15, quad = lane >> 4;
    int rbase = blockIdx.x * 64 + wave * 16;
    int arow = rbase + m;
    size_t rowoff = (size_t)(arow < N_NODES ? arow : 0) * DIM;
    const float* ap2 = xin2 + rowoff;
    const float* aph = h2 + rowoff;

    us8_t a2h[4], a2l[4], ahh[4], ahl[4];
    #pragma unroll
    for (int kt = 0; kt < 4; ++kt) {
        f32x4_t p0 = *(const f32x4_t*)(ap2 + kt * 32 + quad * 8);
        f32x4_t p1 = *(const f32x4_t*)(ap2 + kt * 32 + quad * 8 + 4);
        f32x4_t q0 = *(const f32x4_t*)(aph + kt * 32 + quad * 8);
        f32x4_t q1 = *(const f32x4_t*)(aph + kt * 32 + quad * 8 + 4);
        #pragma unroll
        for (int j = 0; j < 4; ++j) {
            unsigned short h0 = f2b(p0[j]), h1 = f2b(p1[j]);
            a2h[kt][j] = h0; a2h[kt][4 + j] = h1;
            a2l[kt][j] = f2b(p0[j] - b2f(h0));
            a2l[kt][4 + j] = f2b(p1[j] - b2f(h1));
            unsigned short g0 = f2b(q0[j]), g1 = f2b(q1[j]);
            ahh[kt][j] = g0; ahh[kt][4 + j] = g1;
            ahl[kt][j] = f2b(q0[j] - b2f(g0));
            ahl[kt][4 + j] = f2b(q1[j] - b2f(g1));
        }
    }

    f32x4_t acc2[3] = {};
    f32x4_t accp[3] = {};
    #pragma unroll
    for (int kt = 0; kt < 4; ++kt) {
        #pragma unroll
        for (int nt = 0; nt < 3; ++nt) {
            int boff = (nt * 16 + m) * 136 + kt * 32 + quad * 8;
            us8_t b2hv = *(const us8_t*)(&W2Th[boff]);
            us8_t b2lv = *(const us8_t*)(&W2Tl[boff]);
            us8_t bphv = *(const us8_t*)(&WPTh[boff]);
            us8_t bplv = *(const us8_t*)(&WPTl[boff]);
            acc2[nt] = __builtin_amdgcn_mfma_f32_16x16x32_bf16(
                __builtin_bit_cast(bf16x8_t, a2h[kt]),
                __builtin_bit_cast(bf16x8_t, b2hv), acc2[nt], 0, 0, 0);
            acc2[nt] = __builtin_amdgcn_mfma_f32_16x16x32_bf16(
                __builtin_bit_cast(bf16x8_t, a2h[kt]),
                __builtin_bit_cast(bf16x8_t, b2lv), acc2[nt], 0, 0, 0);
            acc2[nt] = __builtin_amdgcn_mfma_f32_16x16x32_bf16(
                __builtin_bit_cast(bf16x8_t, a2l[kt]),
                __builtin_bit_cast(bf16x8_t, b2hv), acc2[nt], 0, 0, 0);
            accp[nt] = __builtin_amdgcn_mfma_f32_16x16x32_bf16(
                __builtin_bit_cast(bf16x8_t, ahh[kt]),
                __builtin_bit_cast(bf16x8_t, bphv), accp[nt], 0, 0, 0);
            accp[nt] = __builtin_amdgcn_mfma_f32_16x16x32_bf16(
                __builtin_bit_cast(bf16x8_t, ahh[kt]),
                __builtin_bit_cast(bf16x8_t, bplv), accp[nt], 0, 0, 0);
            accp[nt] = __builtin_amdgcn_mfma_f32_16x16x32_bf16(
                __builtin_bit_cast(bf16x8_t, ahl[kt]),
                __builtin_bit_cast(bf16x8_t, bphv), accp[nt], 0, 0, 0);
        }
    }

    #pragma unroll
    for (int nt = 0; nt < 3; ++nt) {
        int j = nt * 16 + m;
        int jc = (j < NCLS) ? j : (NCLS - 1);
        float b2j = b2[jc];
        float sc = g2[jc] * rsqrtf(rv2[jc] + 1e-5f);
        float sh = be2[jc] - rm2[jc] * sc;
        float bpj = bp[jc];
        #pragma unroll
        for (int i = 0; i < 4; ++i) {
            int r = rbase + quad * 4 + i;
            if (r < N_NODES && j < NCLS) {
                float z = fmaxf((acc2[nt][i] + b2j) * sc + sh, 0.f);
                float p = accp[nt][i] + bpj;
                out[(size_t)r * NCLS + j] = (p + z) * 0.5f;
            }
        }
    }
}

extern "C" void kernel_launch(void* const* d_in, const int* in_sizes, int n_in,
                              void* d_out, int out_size, void* d_ws, size_t ws_size,
                              hipStream_t stream) {
    const float* h    = (const float*)d_in[0];
    const int* esrc   = (const int*)d_in[1];
    const int* edst   = (const int*)d_in[2];
    const float* mask = (const float*)d_in[3];
    const float* w0   = (const float*)d_in[4];
    const float* b0   = (const float*)d_in[5];
    const float* g0   = (const float*)d_in[6];
    const float* be0  = (const float*)d_in[7];
    const float* rm0  = (const float*)d_in[8];
    const float* rv0  = (const float*)d_in[9];
    const float* w1   = (const float*)d_in[10];
    const float* b1   = (const float*)d_in[11];
    const float* g1   = (const float*)d_in[12];
    const float* be1  = (const float*)d_in[13];
    const float* rm1  = (const float*)d_in[14];
    const float* rv1  = (const float*)d_in[15];
    const float* w2   = (const float*)d_in[16];
    const float* b2   = (const float*)d_in[17];
    const float* g2   = (const float*)d_in[18];
    const float* be2  = (const float*)d_in[19];
    const float* rm2  = (const float*)d_in[20];
    const float* rv2  = (const float*)d_in[21];
    const float* wp   = (const float*)d_in[22];
    const float* bp   = (const float*)d_in[23];

    char* ws = (char*)d_ws;
    size_t off = 0;
    auto alloc = [&](size_t bytes) {
        char* p = ws + off;
        off = (off + bytes + 255) & ~(size_t)255;
        return p;
    };
    int* deg      = (int*)alloc(N_NODES * 4);
    int* rs       = (int*)alloc(N_NODES * 4);
    int* cursor   = (int*)alloc(N_NODES * 4);
    float* dinv   = (float*)alloc(N_NODES * 4);
    int* partial  = (int*)alloc(256 * 4);
    int* blk_off  = (int*)alloc(256 * 4);
    unsigned* csr = (unsigned*)alloc((size_t)N_EDGES * 4);
    float* xin    = (float*)alloc((size_t)N_NODES * DIM * 4);
    float* hb     = (float*)alloc((size_t)N_NODES * DIM * 4);
    unsigned short* xb16 = (unsigned short*)alloc((size_t)N_NODES * DIM * 2);
    unsigned short* hb16 = (unsigned short*)alloc((size_t)N_NODES * DIM * 2);

    hipMemsetAsync(deg, 0, N_NODES * 4, stream);

    const int EB = (N_EDGES + 255) / 256;     // 3125; also covers 6.4M bf16 elems at 8/thread
    const int AB = (N_NODES + 3) / 4;
    const int GB = (N_NODES + 63) / 64;

    prep_kernel<<<EB, 256, 0, stream>>>(edst, deg, h, xb16);
    scan_partial<<<SCAN_BLK, 256, 0, stream>>>(deg, partial);
    scan_blocks<<<1, 256, 0, stream>>>(partial, blk_off);
    scan_final<<<SCAN_BLK, 256, 0, stream>>>(deg, blk_off, rs, cursor, dinv);
    fill_csr<<<EB, 256, 0, stream>>>(esrc, edst, mask, cursor, csr);

    // layer 0
    agg_kernel<<<AB, 256, 0, stream>>>(xb16, h, xin, rs, deg, dinv, csr);
    gemm128_bn_relu<<<GB, 256, 0, stream>>>(xin, w0, b0, g0, be0, rm0, rv0, hb, hb16);
    // layer 1
    agg_kernel<<<AB, 256, 0, stream>>>(hb16, hb, xin, rs, deg, dinv, csr);
    gemm128_bn_relu<<<GB, 256, 0, stream>>>(xin, w1, b1, g1, be1, rm1, rv1, hb, hb16);
    // layer 2 + predict, fused
    agg_kernel<<<AB, 256, 0, stream>>>(hb16, hb, xin, rs, deg, dinv, csr);
    fused_final<<<GB, 256, 0, stream>>>(xin, hb, w2, wp, b2, g2, be2, rm2, rv2, bp,
                                        (float*)d_out);
}